// Round 15
// baseline (1999.430 us; speedup 1.0000x reference)
//
#include <hip/hip_runtime.h>
#include <stdint.h>

typedef float v2f __attribute__((ext_vector_type(2)));

namespace {
constexpr int kB = 64, kS = 512, kD = 768, kH = 3, kDK = 64;
constexpr int kTAG = 33, kNB = 8, kSTART = 31, kSTOP = 32;
constexpr float kNEG = -1e30f;
constexpr size_t kHead = (size_t)kB * kH * kS * kDK;      // 6,291,456 floats per Q/K/V/OA buffer
constexpr size_t kQOFF = 0, kKOFF = kHead, kVOFF = 2 * kHead, kOAOFF = 3 * kHead;
constexpr size_t kWsNeed = 4 * kHead * sizeof(float);     // ~100.7 MB
constexpr size_t kBpsByte = (size_t)kB * kS * kTAG * 4;   // BPS (u16) byte offset inside dead Q region
}

// ---------------- K1: QKV projection, f32 SIMT GEMM (BM=256,BN=64,BK=32) ----
__global__ __launch_bounds__(256) void k_qkv(
    const float* __restrict__ X, const float* __restrict__ wq,
    const float* __restrict__ wk, const float* __restrict__ wv,
    float* __restrict__ ws)
{
  __shared__ __align__(16) float As[32][260];   // [k][row], +4 pad
  __shared__ __align__(16) float Bs[32][68];    // [k][col], +4 pad
  const int bx = blockIdx.y;            // 0..8 -> (type, head)
  const int m0 = blockIdx.x * 256;
  const int tid = threadIdx.x;
  const int tx = tid & 7, ty = tid >> 3;        // col-group 0..7, row-group 0..31
  const int typ = bx / 3, h = bx % 3;
  const float* wptr = (typ == 0) ? wq : (typ == 1) ? wk : wv;
  float* outp = ws + ((typ == 0) ? kQOFF : (typ == 1) ? kKOFF : kVOFF);

  v2f acc2[8][4] = {};
  const int r0 = ty * 8, c0 = tx * 8;
  for (int k0 = 0; k0 < kD; k0 += 32) {
    #pragma unroll
    for (int q = 0; q < 8; ++q) {
      const int flat = q * 256 + tid;
      const int r = flat >> 3, kc = (flat & 7) * 4;
      const float4 v = *(const float4*)(X + (size_t)(m0 + r) * kD + k0 + kc);
      As[kc + 0][r] = v.x; As[kc + 1][r] = v.y; As[kc + 2][r] = v.z; As[kc + 3][r] = v.w;
    }
    #pragma unroll
    for (int q = 0; q < 2; ++q) {
      const int flat = q * 256 + tid;
      const int kk = flat >> 4, c4 = (flat & 15) * 4;
      *(float4*)&Bs[kk][c4] =
          *(const float4*)(wptr + ((size_t)h * kD + k0 + kk) * 64 + c4);
    }
    __syncthreads();
    #pragma unroll
    for (int kk = 0; kk < 32; ++kk) {
      const float4 a0 = *(const float4*)&As[kk][r0];
      const float4 a1 = *(const float4*)&As[kk][r0 + 4];
      const float4 b0 = *(const float4*)&Bs[kk][c0];
      const float4 b1 = *(const float4*)&Bs[kk][c0 + 4];
      const float a[8] = {a0.x, a0.y, a0.z, a0.w, a1.x, a1.y, a1.z, a1.w};
      const v2f bp[4] = {{b0.x, b0.y}, {b0.z, b0.w}, {b1.x, b1.y}, {b1.z, b1.w}};
      #pragma unroll
      for (int i = 0; i < 8; ++i) {
        const v2f ai = {a[i], a[i]};
        #pragma unroll
        for (int jj = 0; jj < 4; ++jj)
          acc2[i][jj] = __builtin_elementwise_fma(ai, bp[jj], acc2[i][jj]);
      }
    }
    __syncthreads();
  }
  #pragma unroll
  for (int i = 0; i < 8; ++i) {
    const int m = m0 + r0 + i;
    const int b = m >> 9, s = m & 511;
    float* dst = outp + ((size_t)(b * kH + h) * kS + s) * kDK + c0;
    *(float4*)dst = make_float4(acc2[i][0].x, acc2[i][0].y, acc2[i][1].x, acc2[i][1].y);
    *(float4*)(dst + 4) = make_float4(acc2[i][2].x, acc2[i][2].y, acc2[i][3].x, acc2[i][3].y);
  }
}

// ---------------- K2: flash-style attention, 64 q-rows per block ------------
__global__ __launch_bounds__(256) void k_attn(
    const float* __restrict__ Q, const float* __restrict__ K,
    const float* __restrict__ V, float* __restrict__ oa)
{
  __shared__ float Qt[64][68];
  __shared__ float Kt[64][68];
  __shared__ float Vl[64][68];
  __shared__ float Pl[64][68];
  const int qt = blockIdx.z, h = blockIdx.y, b = blockIdx.x;
  const int tid = threadIdx.x;
  const int tx = tid & 15, ty = tid >> 4;
  const int r0 = ty * 4, c0 = tx * 4;
  const size_t base = (size_t)(b * kH + h) * kS * kDK;

  {
    const int row = tid >> 2, cc = (tid & 3) * 4;
    const float* src = Q + base + (size_t)(qt * 64 + row) * kDK;
    #pragma unroll
    for (int q = 0; q < 4; ++q) {
      const int c = cc + q * 16;
      const float4 v = *(const float4*)(src + c);
      Qt[c + 0][row] = v.x; Qt[c + 1][row] = v.y; Qt[c + 2][row] = v.z; Qt[c + 3][row] = v.w;
    }
  }
  float m_r[4], l_r[4];
  v2f O2[4][2];
  #pragma unroll
  for (int i = 0; i < 4; ++i) {
    m_r[i] = -__builtin_huge_valf(); l_r[i] = 0.f;
    O2[i][0] = (v2f){0.f, 0.f}; O2[i][1] = (v2f){0.f, 0.f};
  }
  for (int kt = 0; kt < 8; ++kt) {
    __syncthreads();
    {
      const int row = tid >> 2, cc = (tid & 3) * 4;
      const float* srck = K + base + (size_t)(kt * 64 + row) * kDK;
      const float* srcv = V + base + (size_t)(kt * 64 + row) * kDK;
      #pragma unroll
      for (int q = 0; q < 4; ++q) {
        const int c = cc + q * 16;
        const float4 v = *(const float4*)(srck + c);
        Kt[c + 0][row] = v.x; Kt[c + 1][row] = v.y; Kt[c + 2][row] = v.z; Kt[c + 3][row] = v.w;
        *(float4*)&Vl[row][c] = *(const float4*)(srcv + c);
      }
    }
    __syncthreads();
    v2f sc2[4][2] = {};
    for (int k = 0; k < 64; ++k) {
      const float4 a = *(const float4*)&Qt[k][r0];
      const float4 bb = *(const float4*)&Kt[k][c0];
      const float av[4] = {a.x, a.y, a.z, a.w};
      const v2f b01 = {bb.x, bb.y}, b23 = {bb.z, bb.w};
      #pragma unroll
      for (int i = 0; i < 4; ++i) {
        const v2f ai = {av[i], av[i]};
        sc2[i][0] = __builtin_elementwise_fma(ai, b01, sc2[i][0]);
        sc2[i][1] = __builtin_elementwise_fma(ai, b23, sc2[i][1]);
      }
    }
    float sc[4][4];
    #pragma unroll
    for (int i = 0; i < 4; ++i) {
      sc[i][0] = sc2[i][0].x; sc[i][1] = sc2[i][0].y;
      sc[i][2] = sc2[i][1].x; sc[i][3] = sc2[i][1].y;
    }
    #pragma unroll
    for (int i = 0; i < 4; ++i) {
      #pragma unroll
      for (int j = 0; j < 4; ++j) sc[i][j] *= 0.125f;   // /sqrt(64), exact
      float tm = fmaxf(fmaxf(sc[i][0], sc[i][1]), fmaxf(sc[i][2], sc[i][3]));
      #pragma unroll
      for (int m = 1; m < 16; m <<= 1) tm = fmaxf(tm, __shfl_xor(tm, m, 16));
      const float mn = fmaxf(m_r[i], tm);
      const float corr = expf(m_r[i] - mn);              // first tile: exp(-inf)=0
      float ts = 0.f;
      #pragma unroll
      for (int j = 0; j < 4; ++j) { sc[i][j] = expf(sc[i][j] - mn); ts += sc[i][j]; }
      #pragma unroll
      for (int m = 1; m < 16; m <<= 1) ts += __shfl_xor(ts, m, 16);
      l_r[i] = l_r[i] * corr + ts;
      m_r[i] = mn;
      const v2f c2 = {corr, corr};
      O2[i][0] = O2[i][0] * c2;
      O2[i][1] = O2[i][1] * c2;
    }
    #pragma unroll
    for (int j = 0; j < 4; ++j)
      *(float4*)&Pl[c0 + j][r0] = make_float4(sc[0][j], sc[1][j], sc[2][j], sc[3][j]);
    __syncthreads();
    for (int c = 0; c < 64; ++c) {
      const float4 a = *(const float4*)&Pl[c][r0];
      const float4 bb = *(const float4*)&Vl[c][c0];
      const float av[4] = {a.x, a.y, a.z, a.w};
      const v2f b01 = {bb.x, bb.y}, b23 = {bb.z, bb.w};
      #pragma unroll
      for (int i = 0; i < 4; ++i) {
        const v2f ai = {av[i], av[i]};
        O2[i][0] = __builtin_elementwise_fma(ai, b01, O2[i][0]);
        O2[i][1] = __builtin_elementwise_fma(ai, b23, O2[i][1]);
      }
    }
  }
  #pragma unroll
  for (int i = 0; i < 4; ++i) {
    const int s = qt * 64 + r0 + i;
    *(float4*)(oa + ((size_t)(b * kS + s) * kH + h) * 64 + c0) =
        make_float4(O2[i][0].x / l_r[i], O2[i][0].y / l_r[i],
                    O2[i][1].x / l_r[i], O2[i][1].y / l_r[i]);
  }
}

// ------- K3: fused proj + residual + LayerNorm(ddof=1) + lin1/tanh + lin2 ---
__global__ __launch_bounds__(256) void k_head(
    const float* __restrict__ X, const float* __restrict__ oa,
    const float* __restrict__ pw, const float* __restrict__ pb,
    const float* __restrict__ lng, const float* __restrict__ lnb,
    const float* __restrict__ w1, const float* __restrict__ b1,
    const float* __restrict__ w2, const float* __restrict__ b2,
    float* __restrict__ logits)
{
  constexpr int XLP = 776;   // xl row stride (floats)
  constexpr int OALP = 200;  // oal row stride inside union
  constexpr int HLP = 392;   // hl row stride inside union
  __shared__ __align__(16) float xl[16 * XLP];
  __shared__ __align__(16) float uni[16 * HLP];   // oal (proj) then hl (lin1/2)
  const int tid = threadIdx.x;
  const int row0 = blockIdx.x * 16;
  {
    const int r = tid >> 4, seg = tid & 15;
    const float* src = X + (size_t)(row0 + r) * kD;
    #pragma unroll
    for (int q = 0; q < 12; ++q) {
      const int c4 = seg + q * 16;
      *(float4*)&xl[r * XLP + c4 * 4] = *(const float4*)(src + c4 * 4);
    }
    const float* srco = oa + (size_t)(row0 + r) * 192;
    #pragma unroll
    for (int q = 0; q < 3; ++q) {
      const int c4 = seg + q * 16;
      *(float4*)&uni[r * OALP + c4 * 4] = *(const float4*)(srco + c4 * 4);
    }
  }
  __syncthreads();
  // ---- proj: [16 x 192] @ [192 x 768] + bias + residual, 4 cols/thread ----
  if (tid < 192) {
    const int cc = tid * 4;
    v2f accA[16] = {}, accB[16] = {};
    for (int k = 0; k < 192; k += 4) {
      v2f wA[4], wB[4];
      #pragma unroll
      for (int q = 0; q < 4; ++q) {
        wA[q] = *(const v2f*)(pw + (size_t)(k + q) * kD + cc);
        wB[q] = *(const v2f*)(pw + (size_t)(k + q) * kD + cc + 2);
      }
      #pragma unroll
      for (int r = 0; r < 16; ++r) {
        const float4 o4 = *(const float4*)&uni[r * OALP + k];
        accA[r] = __builtin_elementwise_fma((v2f){o4.x, o4.x}, wA[0], accA[r]);
        accB[r] = __builtin_elementwise_fma((v2f){o4.x, o4.x}, wB[0], accB[r]);
        accA[r] = __builtin_elementwise_fma((v2f){o4.y, o4.y}, wA[1], accA[r]);
        accB[r] = __builtin_elementwise_fma((v2f){o4.y, o4.y}, wB[1], accB[r]);
        accA[r] = __builtin_elementwise_fma((v2f){o4.z, o4.z}, wA[2], accA[r]);
        accB[r] = __builtin_elementwise_fma((v2f){o4.z, o4.z}, wB[2], accB[r]);
        accA[r] = __builtin_elementwise_fma((v2f){o4.w, o4.w}, wA[3], accA[r]);
        accB[r] = __builtin_elementwise_fma((v2f){o4.w, o4.w}, wB[3], accB[r]);
      }
    }
    const v2f pbA = *(const v2f*)(pb + cc);
    const v2f pbB = *(const v2f*)(pb + cc + 2);
    #pragma unroll
    for (int r = 0; r < 16; ++r) {
      const float4 res = *(const float4*)&xl[r * XLP + cc];
      const v2f oA = accA[r] + pbA + (v2f){res.x, res.y};
      const v2f oB = accB[r] + pbB + (v2f){res.z, res.w};
      *(float4*)&xl[r * XLP + cc] = make_float4(oA.x, oA.y, oB.x, oB.y);
    }
  }
  __syncthreads();
  // ---- LayerNorm (ddof=1), row per 16-lane group ----
  {
    const int rr = tid >> 4, g = tid & 15;
    float sm = 0.f;
    #pragma unroll
    for (int q = 0; q < 48; ++q) sm += xl[rr * XLP + g + q * 16];
    #pragma unroll
    for (int m = 1; m < 16; m <<= 1) sm += __shfl_xor(sm, m, 16);
    const float mu = sm / 768.0f;
    float s2 = 0.f;
    #pragma unroll
    for (int q = 0; q < 48; ++q) { const float d = xl[rr * XLP + g + q * 16] - mu; s2 += d * d; }
    #pragma unroll
    for (int m = 1; m < 16; m <<= 1) s2 += __shfl_xor(s2, m, 16);
    const float den = sqrtf(s2 / 767.0f) + 1e-3f;   // std(ddof=1) + eps
    #pragma unroll
    for (int q = 0; q < 48; ++q) {
      const int c = g + q * 16;
      xl[rr * XLP + c] = (xl[rr * XLP + c] - mu) / den * lng[c] + lnb[c];
    }
  }
  __syncthreads();
  // ---- lin1: [16 x 768] @ [768 x 384], tanh, column pairs, one pass ----
  if (tid < 192) {
    const int cc = tid * 2;
    v2f acc2[16] = {};
    for (int k = 0; k < 768; k += 4) {
      v2f w2[4];
      #pragma unroll
      for (int q = 0; q < 4; ++q)
        w2[q] = *(const v2f*)(w1 + (size_t)(k + q) * 384 + cc);
      #pragma unroll
      for (int r = 0; r < 16; ++r) {
        const float4 x4 = *(const float4*)&xl[r * XLP + k];
        acc2[r] = __builtin_elementwise_fma((v2f){x4.x, x4.x}, w2[0], acc2[r]);
        acc2[r] = __builtin_elementwise_fma((v2f){x4.y, x4.y}, w2[1], acc2[r]);
        acc2[r] = __builtin_elementwise_fma((v2f){x4.z, x4.z}, w2[2], acc2[r]);
        acc2[r] = __builtin_elementwise_fma((v2f){x4.w, x4.w}, w2[3], acc2[r]);
      }
    }
    const v2f bv2 = *(const v2f*)(b1 + cc);
    #pragma unroll
    for (int r = 0; r < 16; ++r) {
      uni[r * HLP + cc + 0] = tanhf(acc2[r].x + bv2.x);
      uni[r * HLP + cc + 1] = tanhf(acc2[r].y + bv2.y);
    }
  }
  __syncthreads();
  // ---- lin2: [16 x 384] @ [384 x 33] ----
  for (int idx = tid; idx < 16 * kTAG; idx += 256) {
    const int r = idx / kTAG, j = idx - r * kTAG;
    float acc = 0.f;
    for (int k = 0; k < 384; k += 4) {
      const float4 h4 = *(const float4*)&uni[r * HLP + k];
      acc += h4.x * w2[(size_t)(k + 0) * kTAG + j];
      acc += h4.y * w2[(size_t)(k + 1) * kTAG + j];
      acc += h4.z * w2[(size_t)(k + 2) * kTAG + j];
      acc += h4.w * w2[(size_t)(k + 3) * kTAG + j];
    }
    logits[(size_t)(row0 + r) * kTAG + j] = acc + b2[j];
  }
}

// ---------------- K4: Viterbi beam DP — 31x31, f64 keys, SW-pipelined -------
// v8 (single change vs r14): software pipeline. Per iteration t:
//   issue B(t) row/trans loads (L known from last iter) -> compute A(t+1)
//   (independent, reads heads[t&1]) -> B(t) merge (loads returned) -> barrier.
// Enabled by: head of row j at step t == val(a[0]) from phase A == phase B's
// vout[0] (partition rows sorted desc; f32 +s is monotone) -> A(t+1) needs
// only the tiny heads[2][31] array, written by A(t). Pure reorder of the
// identical computation -> results bit-identical to r14.
__device__ __forceinline__ double vk_keyd(float v, unsigned idxf) {
  unsigned u = __float_as_uint(v);
  u = (u & 0x80000000u) ? ~u : (u | 0x80000000u);
  const unsigned long long k = ((unsigned long long)u << 31) | idxf;
  return __longlong_as_double((long long)k);
}
__device__ __forceinline__ float vk_vald(double d) {
  const unsigned long long k = (unsigned long long)__double_as_longlong(d);
  unsigned u = (unsigned)(k >> 31);
  u = (u & 0x80000000u) ? (u & 0x7fffffffu) : ~u;
  return __uint_as_float(u);
}
__device__ __forceinline__ int vk_idxd(double d) {
  const unsigned long long k = (unsigned long long)__double_as_longlong(d);
  return (int)(0x7FFFFFFFu - ((unsigned)k & 0x7FFFFFFFu));
}
template <int CTRL>
__device__ __forceinline__ double dppd(double v) {
  const unsigned long long k = (unsigned long long)__double_as_longlong(v);
  const unsigned lo = (unsigned)__builtin_amdgcn_update_dpp((int)(unsigned)k, (int)(unsigned)k, CTRL, 0xF, 0xF, false);
  const unsigned hi = (unsigned)__builtin_amdgcn_update_dpp((int)(unsigned)(k >> 32), (int)(unsigned)(k >> 32), CTRL, 0xF, 0xF, false);
  return __longlong_as_double((long long)(((unsigned long long)hi << 32) | lo));
}
__device__ __forceinline__ void cedd(double& a, double& b) {
  const double mx = fmax(a, b), mn = fmin(a, b);
  a = mx; b = mn;
}
template <int CTRL>
__device__ __forceinline__ void bmerged(double a[8]) {
  double b[8];
  #pragma unroll
  for (int i = 0; i < 8; ++i) b[i] = dppd<CTRL>(a[i]);
  double w[8];
  #pragma unroll
  for (int i = 0; i < 8; ++i) w[i] = fmax(a[i], b[7 - i]);
  cedd(w[0], w[4]); cedd(w[1], w[5]); cedd(w[2], w[6]); cedd(w[3], w[7]);
  cedd(w[0], w[2]); cedd(w[1], w[3]); cedd(w[4], w[6]); cedd(w[5], w[7]);
  cedd(w[0], w[1]); cedd(w[2], w[3]); cedd(w[4], w[5]); cedd(w[6], w[7]);
  #pragma unroll
  for (int i = 0; i < 8; ++i) a[i] = w[i];
}

// Phase A over head values: sorted top-8 head keys; lane g gets the g-th best
// head's list id L; *newhead = value of the best (== new partition head).
__device__ __forceinline__ int phaseA_d(
    const float* __restrict__ heads, float lg,
    const float tr[4], const int ii[4], const bool vld[4],
    bool g1, bool g2, bool g4, float* newhead)
{
  double a[8];
  #pragma unroll
  for (int c = 0; c < 4; ++c) {
    const float s = lg + tr[c];
    a[c] = vld[c] ? vk_keyd(s + heads[ii[c]], 0x7FFFFFFFu - (unsigned)(ii[c] * 8)) : 0.0;
  }
  a[4] = a[5] = a[6] = a[7] = 0.0;
  cedd(a[0], a[2]); cedd(a[1], a[3]); cedd(a[0], a[1]); cedd(a[2], a[3]); cedd(a[1], a[2]);
  bmerged<0xB1>(a);
  bmerged<0x4E>(a);
  bmerged<0x141>(a);
  *newhead = vk_vald(a[0]);
  const unsigned l0 = (unsigned)__double_as_longlong(a[0]);
  const unsigned l1 = (unsigned)__double_as_longlong(a[1]);
  const unsigned l2 = (unsigned)__double_as_longlong(a[2]);
  const unsigned l3 = (unsigned)__double_as_longlong(a[3]);
  const unsigned l4 = (unsigned)__double_as_longlong(a[4]);
  const unsigned l5 = (unsigned)__double_as_longlong(a[5]);
  const unsigned l6 = (unsigned)__double_as_longlong(a[6]);
  const unsigned l7 = (unsigned)__double_as_longlong(a[7]);
  const unsigned lo01 = g1 ? l1 : l0;
  const unsigned lo23 = g1 ? l3 : l2;
  const unsigned lo45 = g1 ? l5 : l4;
  const unsigned lo67 = g1 ? l7 : l6;
  const unsigned loA = g2 ? lo23 : lo01;
  const unsigned loB = g2 ? lo67 : lo45;
  const unsigned sel = (g4 ? loB : loA) & 0x7FFFFFFFu;
  return (int)((0x7FFFFFFFu - sel) >> 3);
}

// Phase B: lane g merges its full list (row L, preloaded) with the others.
__device__ __forceinline__ void phaseB_d(
    float4 r0, float4 r1, float sB, int L,
    float vout[8], int iout[8])
{
  const unsigned nb = 0x7FFFFFFFu - (unsigned)(L << 3);
  double q[8];
  q[0] = vk_keyd(sB + r0.x, nb - 0); q[1] = vk_keyd(sB + r0.y, nb - 1);
  q[2] = vk_keyd(sB + r0.z, nb - 2); q[3] = vk_keyd(sB + r0.w, nb - 3);
  q[4] = vk_keyd(sB + r1.x, nb - 4); q[5] = vk_keyd(sB + r1.y, nb - 5);
  q[6] = vk_keyd(sB + r1.z, nb - 6); q[7] = vk_keyd(sB + r1.w, nb - 7);
  bmerged<0xB1>(q);
  bmerged<0x4E>(q);
  bmerged<0x141>(q);
  #pragma unroll
  for (int r = 0; r < 8; ++r) {
    vout[r] = vk_vald(q[r]);
    iout[r] = vk_idxd(q[r]);
  }
}

// Full merge (phase A reads row heads from full rows) — used for end merge.
template <bool WITHLG>
__device__ __forceinline__ void merge31(
    const float (*rows)[12], const float* trans_colj, float lg,
    const float tr[4], const int ii[4], const bool vld[4],
    bool g1, bool g2, bool g4,
    float vout[8], int iout[8])
{
  double a[8];
  #pragma unroll
  for (int c = 0; c < 4; ++c) {
    const float s = WITHLG ? (lg + tr[c]) : tr[c];
    a[c] = vld[c] ? vk_keyd(s + rows[ii[c]][0], 0x7FFFFFFFu - (unsigned)(ii[c] * 8)) : 0.0;
  }
  a[4] = a[5] = a[6] = a[7] = 0.0;
  cedd(a[0], a[2]); cedd(a[1], a[3]); cedd(a[0], a[1]); cedd(a[2], a[3]); cedd(a[1], a[2]);
  bmerged<0xB1>(a);
  bmerged<0x4E>(a);
  bmerged<0x141>(a);
  const unsigned l0 = (unsigned)__double_as_longlong(a[0]);
  const unsigned l1 = (unsigned)__double_as_longlong(a[1]);
  const unsigned l2 = (unsigned)__double_as_longlong(a[2]);
  const unsigned l3 = (unsigned)__double_as_longlong(a[3]);
  const unsigned l4 = (unsigned)__double_as_longlong(a[4]);
  const unsigned l5 = (unsigned)__double_as_longlong(a[5]);
  const unsigned l6 = (unsigned)__double_as_longlong(a[6]);
  const unsigned l7 = (unsigned)__double_as_longlong(a[7]);
  const unsigned lo01 = g1 ? l1 : l0;
  const unsigned lo23 = g1 ? l3 : l2;
  const unsigned lo45 = g1 ? l5 : l4;
  const unsigned lo67 = g1 ? l7 : l6;
  const unsigned loA = g2 ? lo23 : lo01;
  const unsigned loB = g2 ? lo67 : lo45;
  const unsigned sel = (g4 ? loB : loA) & 0x7FFFFFFFu;
  const int L = (int)((0x7FFFFFFFu - sel) >> 3);
  const float trL = trans_colj[(size_t)L * kTAG];
  const float sB = WITHLG ? (lg + trL) : trL;
  const float4* prow = (const float4*)&rows[L][0];
  phaseB_d(prow[0], prow[1], sB, L, vout, iout);
}

__global__ __launch_bounds__(256) void k_viterbi(
    const float* __restrict__ logits, const int* __restrict__ mask,
    const float* __restrict__ trans, unsigned short* __restrict__ bps,
    int* __restrict__ lastpos_g, int* __restrict__ ptr0_g)
{
  constexpr int kNT = 31;   // normal tags 0..30
  __shared__ __align__(16) float trans_s[kTAG][kTAG];
  __shared__ __align__(16) float part[2][kNT][12];   // rows padded to 12 floats
  __shared__ __align__(16) float lastp[kNT][12];
  __shared__ float heads_s[2][kNT + 1];              // heads of part[p]
  __shared__ int lastpos_s;
  const int b = blockIdx.x, tid = threadIdx.x;
  for (int idx = tid; idx < kTAG * kTAG; idx += 256)
    trans_s[idx / kTAG][idx % kTAG] = trans[idx];
  if (tid < 64) {
    int sm = 0;
    #pragma unroll
    for (int q = 0; q < 8; ++q) sm += mask[b * kS + tid * 8 + q];
    #pragma unroll
    for (int m = 1; m < 64; m <<= 1) sm += __shfl_xor(sm, m, 64);
    if (tid == 0) { lastpos_s = sm - 1; lastpos_g[b] = sm - 1; }
  }
  const int grp = tid >> 3, g = tid & 7;
  const bool active = (grp < kNT);
  const int j = grp;                       // grp==31 inactive (reads col 31, harmless)
  const bool g1 = g & 1, g2 = g & 2, g4 = g & 4;
  __syncthreads();
  float tr[4]; int ii[4]; bool vld[4];
  #pragma unroll
  for (int c = 0; c < 4; ++c) {
    const int i0 = g + 8 * c;
    vld[c] = (i0 < kNT);
    ii[c] = vld[c] ? i0 : 0;
    tr[c] = trans_s[ii[c]][j];
  }
  if (active) {
    const float h0 = logits[(size_t)b * kS * kTAG + j] + trans_s[kSTART][j];
    part[0][j][g] = (g == 0) ? h0 : kNEG;
    if (g == 0) heads_s[0][j] = h0;
  }
  const int lp = lastpos_s;                // >= 255 (lengths in [S/2, S])
  __syncthreads();                         // part[0]/heads_s[0] visible

  // prologue: A(1)
  int L_cur = 0;
  float lgB = 0.f, lgA = 0.f;
  if (active) {
    const float lg1 = logits[((size_t)b * kS + 1) * kTAG + j];
    float nh;
    L_cur = phaseA_d(heads_s[0], lg1, tr, ii, vld, g1, g2, g4, &nh);
    if (g == 0) heads_s[1][j] = nh;
    lgB = lg1;
    lgA = logits[((size_t)b * kS + 2) * kTAG + j];
  }

  for (int t = 1; t < kS; ++t) {
    __syncthreads();
    if (t <= lp) {
      if (active) {
        // early loads for B(t): row L_cur of part[(t-1)&1] + trans column entry
        const float4* prow = (const float4*)&part[(t - 1) & 1][L_cur][0];
        const float4 rA = prow[0], rB = prow[1];
        const float trL = trans_s[L_cur][j];
        // A(t+1) — independent of B(t)'s loads
        int L_next = L_cur;
        if (t + 1 <= lp) {
          float nh;
          L_next = phaseA_d(heads_s[t & 1], lgA, tr, ii, vld, g1, g2, g4, &nh);
          if (g == 0) heads_s[(t + 1) & 1][j] = nh;
        }
        const float lgP = (t + 2 < kS) ? logits[((size_t)b * kS + t + 2) * kTAG + j] : 0.f;
        // B(t)
        float vout[8]; int iout[8];
        phaseB_d(rA, rB, lgB + trL, L_cur, vout, iout);
        if (g == 0) {
          *(float4*)&part[t & 1][j][0] = make_float4(vout[0], vout[1], vout[2], vout[3]);
          *(float4*)&part[t & 1][j][4] = make_float4(vout[4], vout[5], vout[6], vout[7]);
          if (t == lp) {
            *(float4*)&lastp[j][0] = make_float4(vout[0], vout[1], vout[2], vout[3]);
            *(float4*)&lastp[j][4] = make_float4(vout[4], vout[5], vout[6], vout[7]);
          }
          const unsigned w01 = (unsigned)iout[0] | ((unsigned)iout[1] << 16);
          const unsigned w23 = (unsigned)iout[2] | ((unsigned)iout[3] << 16);
          const unsigned w45 = (unsigned)iout[4] | ((unsigned)iout[5] << 16);
          const unsigned w67 = (unsigned)iout[6] | ((unsigned)iout[7] << 16);
          *(int4*)(bps + ((size_t)t * kB + b) * (kTAG * kNB) + j * kNB) =
              make_int4((int)w01, (int)w23, (int)w45, (int)w67);
        }
        L_cur = L_next; lgB = lgA; lgA = lgP;
      }
    } else if (active && g == 0) {         // dead region: reference stores bp=0
      *(int4*)(bps + ((size_t)t * kB + b) * (kTAG * kNB) + j * kNB) = make_int4(0, 0, 0, 0);
    }
  }
  __syncthreads();
  if (tid < 8) {                           // end merge: column STOP over lastp
    float tre[4];
    #pragma unroll
    for (int c = 0; c < 4; ++c) tre[c] = trans_s[ii[c]][kSTOP];
    float vo[8]; int io[8];
    merge31<false>(lastp, &trans_s[0][kSTOP], 0.f, tre, ii, vld, g1, g2, g4, vo, io);
    if (tid == 0) {
      *(int4*)&ptr0_g[b * kNB + 0] = make_int4(io[0], io[1], io[2], io[3]);
      *(int4*)&ptr0_g[b * kNB + 4] = make_int4(io[4], io[5], io[6], io[7]);
    }
  }
}

// ------- K5: backtrace, per-batch block with LDS-prefetched bp rows ---------
__global__ __launch_bounds__(256) void k_backtrace(
    const unsigned short* __restrict__ bps, const int* __restrict__ ptr0,
    const int* __restrict__ lastpos, const int* __restrict__ mask,
    int* __restrict__ out)
{
  __shared__ uint4 buf[2][4][33];          // 4 rows x 264 u16 per stage
  __shared__ int ptr0_s[kNB];
  __shared__ int mask_s[kS];
  const int b = blockIdx.x, tid = threadIdx.x;
  if (tid < kNB) ptr0_s[tid] = ptr0[b * kNB + tid];
  for (int i = tid; i < kS; i += 256) mask_s[i] = mask[b * kS + i];
  const int lp = lastpos[b];
  const int lr = tid / 33, lc = tid % 33;
  if (tid < 132)
    buf[0][lr][lc] = ((const uint4*)(bps + ((size_t)(kS - 1 - lr) * kB + b) * (kTAG * kNB)))[lc];
  int p = ptr0[b * kNB];
  if (tid == 0) out[b * kS + kS - 1] = p >> 3;
  __syncthreads();
  int cur = 0, tau = kS - 2;
  while (tau >= 0) {
    const int cnt = (tau >= 3) ? 4 : (tau + 1);
    const int ntau = tau - cnt;
    uint4 v; bool have = false;
    if (ntau >= 0 && tid < 132) {
      const int cnt2 = (ntau >= 3) ? 4 : (ntau + 1);
      if (lr < cnt2) {
        v = ((const uint4*)(bps + ((size_t)(ntau + 1 - lr) * kB + b) * (kTAG * kNB)))[lc];
        have = true;
      }
    }
    for (int s2 = 0; s2 < cnt; ++s2) {
      const int t2 = tau - s2;
      int np;
      if (t2 == lp) np = ptr0_s[p & 7];
      else np = ((const unsigned short*)&buf[cur][s2][0])[p];
      if (tid == 0) out[b * kS + t2] = np >> 3;
      p = mask_s[t2] ? np : (np + p);
    }
    __syncthreads();
    if (have) buf[cur ^ 1][lr][lc] = v;
    __syncthreads();
    cur ^= 1; tau = ntau;
  }
}

extern "C" void kernel_launch(void* const* d_in, const int* in_sizes, int n_in,
                              void* d_out, int out_size, void* d_ws, size_t ws_size,
                              hipStream_t stream) {
  if (ws_size < kWsNeed) return;  // fail loudly rather than corrupt memory
  const float* X   = (const float*)d_in[0];
  const int*   msk = (const int*)d_in[1];
  const float* wq  = (const float*)d_in[2];
  const float* wk  = (const float*)d_in[3];
  const float* wv  = (const float*)d_in[4];
  const float* pw  = (const float*)d_in[5];
  const float* pb  = (const float*)d_in[6];
  const float* lng = (const float*)d_in[7];
  const float* lnb = (const float*)d_in[8];
  const float* w1  = (const float*)d_in[9];
  const float* b1  = (const float*)d_in[10];
  const float* w2  = (const float*)d_in[11];
  const float* b2  = (const float*)d_in[12];
  const float* trn = (const float*)d_in[13];
  float* ws = (float*)d_ws;

  k_qkv<<<dim3(128, 9), 256, 0, stream>>>(X, wq, wk, wv, ws);
  k_attn<<<dim3(64, 3, 8), 256, 0, stream>>>(ws + kQOFF, ws + kKOFF, ws + kVOFF, ws + kOAOFF);
  k_head<<<2048, 256, 0, stream>>>(X, ws + kOAOFF, pw, pb, lng, lnb, w1, b1, w2, b2, ws);
  unsigned short* bps = (unsigned short*)((char*)d_ws + kBpsByte);
  int* lastpos_p = (int*)(ws + kKOFF);   // K buffer dead after attention
  int* ptr0_p = lastpos_p + kB;
  k_viterbi<<<kB, 256, 0, stream>>>(ws, msk, trn, bps, lastpos_p, ptr0_p);
  k_backtrace<<<kB, 256, 0, stream>>>(bps, ptr0_p, lastpos_p, msk, (int*)d_out);
}

// Round 16
// 1931.129 us; speedup vs baseline: 1.0354x; 1.0354x over previous
//
#include <hip/hip_runtime.h>
#include <stdint.h>

typedef float v2f __attribute__((ext_vector_type(2)));

namespace {
constexpr int kB = 64, kS = 512, kD = 768, kH = 3, kDK = 64;
constexpr int kTAG = 33, kNB = 8, kSTART = 31, kSTOP = 32;
constexpr float kNEG = -1e30f;
constexpr size_t kHead = (size_t)kB * kH * kS * kDK;      // 6,291,456 floats per Q/K/V/OA buffer
constexpr size_t kQOFF = 0, kKOFF = kHead, kVOFF = 2 * kHead, kOAOFF = 3 * kHead;
constexpr size_t kWsNeed = 4 * kHead * sizeof(float);     // ~100.7 MB
constexpr size_t kBpsByte = (size_t)kB * kS * kTAG * 4;   // BPS (u16) byte offset inside dead Q region
}

// DPP lane-permute for f32 (all lanes active). 0xB1=xor1, 0x4E=xor2,
// 0x141=row_half_mirror (xor7), 0x140=row_mirror (xor15).
template <int CTRL>
__device__ __forceinline__ float dppf(float x) {
  return __uint_as_float((unsigned)__builtin_amdgcn_update_dpp(
      (int)__float_as_uint(x), (int)__float_as_uint(x), CTRL, 0xF, 0xF, false));
}
// 16-lane reductions via DPP. Bit-identical to the xor1/2/4/8 shfl butterfly:
// after xor1+xor2 each quad is bitwise-uniform (fp add/max commutativity),
// so xor7 == xor4 partner value and xor15 == xor8 partner value.
__device__ __forceinline__ float dpp16_max(float x) {
  x = fmaxf(x, dppf<0xB1>(x));
  x = fmaxf(x, dppf<0x4E>(x));
  x = fmaxf(x, dppf<0x141>(x));
  x = fmaxf(x, dppf<0x140>(x));
  return x;
}
__device__ __forceinline__ float dpp16_sum(float x) {
  x += dppf<0xB1>(x);
  x += dppf<0x4E>(x);
  x += dppf<0x141>(x);
  x += dppf<0x140>(x);
  return x;
}

// ---------------- K1: QKV projection, f32 SIMT GEMM (BM=256,BN=64,BK=32) ----
__global__ __launch_bounds__(256) void k_qkv(
    const float* __restrict__ X, const float* __restrict__ wq,
    const float* __restrict__ wk, const float* __restrict__ wv,
    float* __restrict__ ws)
{
  __shared__ __align__(16) float As[32][260];   // [k][row], +4 pad
  __shared__ __align__(16) float Bs[32][68];    // [k][col], +4 pad
  const int bx = blockIdx.y;            // 0..8 -> (type, head)
  const int m0 = blockIdx.x * 256;
  const int tid = threadIdx.x;
  const int tx = tid & 7, ty = tid >> 3;        // col-group 0..7, row-group 0..31
  const int typ = bx / 3, h = bx % 3;
  const float* wptr = (typ == 0) ? wq : (typ == 1) ? wk : wv;
  float* outp = ws + ((typ == 0) ? kQOFF : (typ == 1) ? kKOFF : kVOFF);

  v2f acc2[8][4] = {};
  const int r0 = ty * 8, c0 = tx * 8;
  for (int k0 = 0; k0 < kD; k0 += 32) {
    #pragma unroll
    for (int q = 0; q < 8; ++q) {
      const int flat = q * 256 + tid;
      const int r = flat >> 3, kc = (flat & 7) * 4;
      const float4 v = *(const float4*)(X + (size_t)(m0 + r) * kD + k0 + kc);
      As[kc + 0][r] = v.x; As[kc + 1][r] = v.y; As[kc + 2][r] = v.z; As[kc + 3][r] = v.w;
    }
    #pragma unroll
    for (int q = 0; q < 2; ++q) {
      const int flat = q * 256 + tid;
      const int kk = flat >> 4, c4 = (flat & 15) * 4;
      *(float4*)&Bs[kk][c4] =
          *(const float4*)(wptr + ((size_t)h * kD + k0 + kk) * 64 + c4);
    }
    __syncthreads();
    #pragma unroll
    for (int kk = 0; kk < 32; ++kk) {
      const float4 a0 = *(const float4*)&As[kk][r0];
      const float4 a1 = *(const float4*)&As[kk][r0 + 4];
      const float4 b0 = *(const float4*)&Bs[kk][c0];
      const float4 b1 = *(const float4*)&Bs[kk][c0 + 4];
      const float a[8] = {a0.x, a0.y, a0.z, a0.w, a1.x, a1.y, a1.z, a1.w};
      const v2f bp[4] = {{b0.x, b0.y}, {b0.z, b0.w}, {b1.x, b1.y}, {b1.z, b1.w}};
      #pragma unroll
      for (int i = 0; i < 8; ++i) {
        const v2f ai = {a[i], a[i]};
        #pragma unroll
        for (int jj = 0; jj < 4; ++jj)
          acc2[i][jj] = __builtin_elementwise_fma(ai, bp[jj], acc2[i][jj]);
      }
    }
    __syncthreads();
  }
  #pragma unroll
  for (int i = 0; i < 8; ++i) {
    const int m = m0 + r0 + i;
    const int b = m >> 9, s = m & 511;
    float* dst = outp + ((size_t)(b * kH + h) * kS + s) * kDK + c0;
    *(float4*)dst = make_float4(acc2[i][0].x, acc2[i][0].y, acc2[i][1].x, acc2[i][1].y);
    *(float4*)(dst + 4) = make_float4(acc2[i][2].x, acc2[i][2].y, acc2[i][3].x, acc2[i][3].y);
  }
}

// ---------------- K2: flash-style attention, 64 q-rows per block ------------
// v4: softmax reductions via DPP (VALU) instead of shfl_xor (LDS ops).
// Bit-identical (see dpp16_* comment).
__global__ __launch_bounds__(256) void k_attn(
    const float* __restrict__ Q, const float* __restrict__ K,
    const float* __restrict__ V, float* __restrict__ oa)
{
  __shared__ float Qt[64][68];
  __shared__ float Kt[64][68];
  __shared__ float Vl[64][68];
  __shared__ float Pl[64][68];
  const int qt = blockIdx.z, h = blockIdx.y, b = blockIdx.x;
  const int tid = threadIdx.x;
  const int tx = tid & 15, ty = tid >> 4;
  const int r0 = ty * 4, c0 = tx * 4;
  const size_t base = (size_t)(b * kH + h) * kS * kDK;

  {
    const int row = tid >> 2, cc = (tid & 3) * 4;
    const float* src = Q + base + (size_t)(qt * 64 + row) * kDK;
    #pragma unroll
    for (int q = 0; q < 4; ++q) {
      const int c = cc + q * 16;
      const float4 v = *(const float4*)(src + c);
      Qt[c + 0][row] = v.x; Qt[c + 1][row] = v.y; Qt[c + 2][row] = v.z; Qt[c + 3][row] = v.w;
    }
  }
  float m_r[4], l_r[4];
  v2f O2[4][2];
  #pragma unroll
  for (int i = 0; i < 4; ++i) {
    m_r[i] = -__builtin_huge_valf(); l_r[i] = 0.f;
    O2[i][0] = (v2f){0.f, 0.f}; O2[i][1] = (v2f){0.f, 0.f};
  }
  for (int kt = 0; kt < 8; ++kt) {
    __syncthreads();
    {
      const int row = tid >> 2, cc = (tid & 3) * 4;
      const float* srck = K + base + (size_t)(kt * 64 + row) * kDK;
      const float* srcv = V + base + (size_t)(kt * 64 + row) * kDK;
      #pragma unroll
      for (int q = 0; q < 4; ++q) {
        const int c = cc + q * 16;
        const float4 v = *(const float4*)(srck + c);
        Kt[c + 0][row] = v.x; Kt[c + 1][row] = v.y; Kt[c + 2][row] = v.z; Kt[c + 3][row] = v.w;
        *(float4*)&Vl[row][c] = *(const float4*)(srcv + c);
      }
    }
    __syncthreads();
    v2f sc2[4][2] = {};
    for (int k = 0; k < 64; ++k) {
      const float4 a = *(const float4*)&Qt[k][r0];
      const float4 bb = *(const float4*)&Kt[k][c0];
      const float av[4] = {a.x, a.y, a.z, a.w};
      const v2f b01 = {bb.x, bb.y}, b23 = {bb.z, bb.w};
      #pragma unroll
      for (int i = 0; i < 4; ++i) {
        const v2f ai = {av[i], av[i]};
        sc2[i][0] = __builtin_elementwise_fma(ai, b01, sc2[i][0]);
        sc2[i][1] = __builtin_elementwise_fma(ai, b23, sc2[i][1]);
      }
    }
    float sc[4][4];
    #pragma unroll
    for (int i = 0; i < 4; ++i) {
      sc[i][0] = sc2[i][0].x; sc[i][1] = sc2[i][0].y;
      sc[i][2] = sc2[i][1].x; sc[i][3] = sc2[i][1].y;
    }
    #pragma unroll
    for (int i = 0; i < 4; ++i) {
      #pragma unroll
      for (int j = 0; j < 4; ++j) sc[i][j] *= 0.125f;   // /sqrt(64), exact
      float tm = fmaxf(fmaxf(sc[i][0], sc[i][1]), fmaxf(sc[i][2], sc[i][3]));
      tm = dpp16_max(tm);
      const float mn = fmaxf(m_r[i], tm);
      const float corr = expf(m_r[i] - mn);              // first tile: exp(-inf)=0
      float ts = 0.f;
      #pragma unroll
      for (int j = 0; j < 4; ++j) { sc[i][j] = expf(sc[i][j] - mn); ts += sc[i][j]; }
      ts = dpp16_sum(ts);
      l_r[i] = l_r[i] * corr + ts;
      m_r[i] = mn;
      const v2f c2 = {corr, corr};
      O2[i][0] = O2[i][0] * c2;
      O2[i][1] = O2[i][1] * c2;
    }
    #pragma unroll
    for (int j = 0; j < 4; ++j)
      *(float4*)&Pl[c0 + j][r0] = make_float4(sc[0][j], sc[1][j], sc[2][j], sc[3][j]);
    __syncthreads();
    for (int c = 0; c < 64; ++c) {
      const float4 a = *(const float4*)&Pl[c][r0];
      const float4 bb = *(const float4*)&Vl[c][c0];
      const float av[4] = {a.x, a.y, a.z, a.w};
      const v2f b01 = {bb.x, bb.y}, b23 = {bb.z, bb.w};
      #pragma unroll
      for (int i = 0; i < 4; ++i) {
        const v2f ai = {av[i], av[i]};
        O2[i][0] = __builtin_elementwise_fma(ai, b01, O2[i][0]);
        O2[i][1] = __builtin_elementwise_fma(ai, b23, O2[i][1]);
      }
    }
  }
  #pragma unroll
  for (int i = 0; i < 4; ++i) {
    const int s = qt * 64 + r0 + i;
    *(float4*)(oa + ((size_t)(b * kS + s) * kH + h) * 64 + c0) =
        make_float4(O2[i][0].x / l_r[i], O2[i][0].y / l_r[i],
                    O2[i][1].x / l_r[i], O2[i][1].y / l_r[i]);
  }
}

// ------- K3: fused proj + residual + LayerNorm(ddof=1) + lin1/tanh + lin2 ---
// v5: LN reductions via DPP (bit-identical). Rest unchanged from r13.
__global__ __launch_bounds__(256) void k_head(
    const float* __restrict__ X, const float* __restrict__ oa,
    const float* __restrict__ pw, const float* __restrict__ pb,
    const float* __restrict__ lng, const float* __restrict__ lnb,
    const float* __restrict__ w1, const float* __restrict__ b1,
    const float* __restrict__ w2, const float* __restrict__ b2,
    float* __restrict__ logits)
{
  constexpr int XLP = 776;   // xl row stride (floats)
  constexpr int OALP = 200;  // oal row stride inside union
  constexpr int HLP = 392;   // hl row stride inside union
  __shared__ __align__(16) float xl[16 * XLP];
  __shared__ __align__(16) float uni[16 * HLP];   // oal (proj) then hl (lin1/2)
  const int tid = threadIdx.x;
  const int row0 = blockIdx.x * 16;
  {
    const int r = tid >> 4, seg = tid & 15;
    const float* src = X + (size_t)(row0 + r) * kD;
    #pragma unroll
    for (int q = 0; q < 12; ++q) {
      const int c4 = seg + q * 16;
      *(float4*)&xl[r * XLP + c4 * 4] = *(const float4*)(src + c4 * 4);
    }
    const float* srco = oa + (size_t)(row0 + r) * 192;
    #pragma unroll
    for (int q = 0; q < 3; ++q) {
      const int c4 = seg + q * 16;
      *(float4*)&uni[r * OALP + c4 * 4] = *(const float4*)(srco + c4 * 4);
    }
  }
  __syncthreads();
  // ---- proj: [16 x 192] @ [192 x 768] + bias + residual, 4 cols/thread ----
  if (tid < 192) {
    const int cc = tid * 4;
    v2f accA[16] = {}, accB[16] = {};
    for (int k = 0; k < 192; k += 4) {
      v2f wA[4], wB[4];
      #pragma unroll
      for (int q = 0; q < 4; ++q) {
        wA[q] = *(const v2f*)(pw + (size_t)(k + q) * kD + cc);
        wB[q] = *(const v2f*)(pw + (size_t)(k + q) * kD + cc + 2);
      }
      #pragma unroll
      for (int r = 0; r < 16; ++r) {
        const float4 o4 = *(const float4*)&uni[r * OALP + k];
        accA[r] = __builtin_elementwise_fma((v2f){o4.x, o4.x}, wA[0], accA[r]);
        accB[r] = __builtin_elementwise_fma((v2f){o4.x, o4.x}, wB[0], accB[r]);
        accA[r] = __builtin_elementwise_fma((v2f){o4.y, o4.y}, wA[1], accA[r]);
        accB[r] = __builtin_elementwise_fma((v2f){o4.y, o4.y}, wB[1], accB[r]);
        accA[r] = __builtin_elementwise_fma((v2f){o4.z, o4.z}, wA[2], accA[r]);
        accB[r] = __builtin_elementwise_fma((v2f){o4.z, o4.z}, wB[2], accB[r]);
        accA[r] = __builtin_elementwise_fma((v2f){o4.w, o4.w}, wA[3], accA[r]);
        accB[r] = __builtin_elementwise_fma((v2f){o4.w, o4.w}, wB[3], accB[r]);
      }
    }
    const v2f pbA = *(const v2f*)(pb + cc);
    const v2f pbB = *(const v2f*)(pb + cc + 2);
    #pragma unroll
    for (int r = 0; r < 16; ++r) {
      const float4 res = *(const float4*)&xl[r * XLP + cc];
      const v2f oA = accA[r] + pbA + (v2f){res.x, res.y};
      const v2f oB = accB[r] + pbB + (v2f){res.z, res.w};
      *(float4*)&xl[r * XLP + cc] = make_float4(oA.x, oA.y, oB.x, oB.y);
    }
  }
  __syncthreads();
  // ---- LayerNorm (ddof=1), row per 16-lane group ----
  {
    const int rr = tid >> 4, g = tid & 15;
    float sm = 0.f;
    #pragma unroll
    for (int q = 0; q < 48; ++q) sm += xl[rr * XLP + g + q * 16];
    sm = dpp16_sum(sm);
    const float mu = sm / 768.0f;
    float s2 = 0.f;
    #pragma unroll
    for (int q = 0; q < 48; ++q) { const float d = xl[rr * XLP + g + q * 16] - mu; s2 += d * d; }
    s2 = dpp16_sum(s2);
    const float den = sqrtf(s2 / 767.0f) + 1e-3f;   // std(ddof=1) + eps
    #pragma unroll
    for (int q = 0; q < 48; ++q) {
      const int c = g + q * 16;
      xl[rr * XLP + c] = (xl[rr * XLP + c] - mu) / den * lng[c] + lnb[c];
    }
  }
  __syncthreads();
  // ---- lin1: [16 x 768] @ [768 x 384], tanh, column pairs, one pass ----
  if (tid < 192) {
    const int cc = tid * 2;
    v2f acc2[16] = {};
    for (int k = 0; k < 768; k += 4) {
      v2f w2[4];
      #pragma unroll
      for (int q = 0; q < 4; ++q)
        w2[q] = *(const v2f*)(w1 + (size_t)(k + q) * 384 + cc);
      #pragma unroll
      for (int r = 0; r < 16; ++r) {
        const float4 x4 = *(const float4*)&xl[r * XLP + k];
        acc2[r] = __builtin_elementwise_fma((v2f){x4.x, x4.x}, w2[0], acc2[r]);
        acc2[r] = __builtin_elementwise_fma((v2f){x4.y, x4.y}, w2[1], acc2[r]);
        acc2[r] = __builtin_elementwise_fma((v2f){x4.z, x4.z}, w2[2], acc2[r]);
        acc2[r] = __builtin_elementwise_fma((v2f){x4.w, x4.w}, w2[3], acc2[r]);
      }
    }
    const v2f bv2 = *(const v2f*)(b1 + cc);
    #pragma unroll
    for (int r = 0; r < 16; ++r) {
      uni[r * HLP + cc + 0] = tanhf(acc2[r].x + bv2.x);
      uni[r * HLP + cc + 1] = tanhf(acc2[r].y + bv2.y);
    }
  }
  __syncthreads();
  // ---- lin2: [16 x 384] @ [384 x 33] ----
  for (int idx = tid; idx < 16 * kTAG; idx += 256) {
    const int r = idx / kTAG, j = idx - r * kTAG;
    float acc = 0.f;
    for (int k = 0; k < 384; k += 4) {
      const float4 h4 = *(const float4*)&uni[r * HLP + k];
      acc += h4.x * w2[(size_t)(k + 0) * kTAG + j];
      acc += h4.y * w2[(size_t)(k + 1) * kTAG + j];
      acc += h4.z * w2[(size_t)(k + 2) * kTAG + j];
      acc += h4.w * w2[(size_t)(k + 3) * kTAG + j];
    }
    logits[(size_t)(row0 + r) * kTAG + j] = acc + b2[j];
  }
}

// ---------------- K4: Viterbi beam DP — 31x31, f64-packed keys (r14) --------
// REVERTED to the verified r14 version (750 us). SW-pipeline (r15) was
// neutral-to-negative: compiler already hoists phase-B ds_reads; declared at
// structural floor (~55% issue / 45% serial DPP+f64max chains).
__device__ __forceinline__ double vk_keyd(float v, unsigned idxf) {
  unsigned u = __float_as_uint(v);
  u = (u & 0x80000000u) ? ~u : (u | 0x80000000u);
  const unsigned long long k = ((unsigned long long)u << 31) | idxf;
  return __longlong_as_double((long long)k);
}
__device__ __forceinline__ float vk_vald(double d) {
  const unsigned long long k = (unsigned long long)__double_as_longlong(d);
  unsigned u = (unsigned)(k >> 31);
  u = (u & 0x80000000u) ? (u & 0x7fffffffu) : ~u;
  return __uint_as_float(u);
}
__device__ __forceinline__ int vk_idxd(double d) {
  const unsigned long long k = (unsigned long long)__double_as_longlong(d);
  return (int)(0x7FFFFFFFu - ((unsigned)k & 0x7FFFFFFFu));
}
template <int CTRL>
__device__ __forceinline__ double dppd(double v) {
  const unsigned long long k = (unsigned long long)__double_as_longlong(v);
  const unsigned lo = (unsigned)__builtin_amdgcn_update_dpp((int)(unsigned)k, (int)(unsigned)k, CTRL, 0xF, 0xF, false);
  const unsigned hi = (unsigned)__builtin_amdgcn_update_dpp((int)(unsigned)(k >> 32), (int)(unsigned)(k >> 32), CTRL, 0xF, 0xF, false);
  return __longlong_as_double((long long)(((unsigned long long)hi << 32) | lo));
}
__device__ __forceinline__ void cedd(double& a, double& b) {
  const double mx = fmax(a, b), mn = fmin(a, b);
  a = mx; b = mn;
}
template <int CTRL>
__device__ __forceinline__ void bmerged(double a[8]) {
  double b[8];
  #pragma unroll
  for (int i = 0; i < 8; ++i) b[i] = dppd<CTRL>(a[i]);
  double w[8];
  #pragma unroll
  for (int i = 0; i < 8; ++i) w[i] = fmax(a[i], b[7 - i]);
  cedd(w[0], w[4]); cedd(w[1], w[5]); cedd(w[2], w[6]); cedd(w[3], w[7]);
  cedd(w[0], w[2]); cedd(w[1], w[3]); cedd(w[4], w[6]); cedd(w[5], w[7]);
  cedd(w[0], w[1]); cedd(w[2], w[3]); cedd(w[4], w[5]); cedd(w[6], w[7]);
  #pragma unroll
  for (int i = 0; i < 8; ++i) a[i] = w[i];
}

// Exact top-8 of 248 candidates cand[i*8+n] = s_i + rows[i][n] over i=0..30.
template <bool WITHLG>
__device__ __forceinline__ void merge31(
    const float (*rows)[12], const float* trans_colj, float lg,
    const float tr[4], const int ii[4], const bool vld[4],
    bool g1, bool g2, bool g4,
    float vout[8], int iout[8])
{
  double a[8];
  #pragma unroll
  for (int c = 0; c < 4; ++c) {
    const float s = WITHLG ? (lg + tr[c]) : tr[c];
    a[c] = vld[c] ? vk_keyd(s + rows[ii[c]][0], 0x7FFFFFFFu - (unsigned)(ii[c] * 8)) : 0.0;
  }
  a[4] = a[5] = a[6] = a[7] = 0.0;
  // sort4 desc (5-CE Batcher)
  cedd(a[0], a[2]); cedd(a[1], a[3]); cedd(a[0], a[1]); cedd(a[2], a[3]); cedd(a[1], a[2]);
  bmerged<0xB1>(a);   // lane^1
  bmerged<0x4E>(a);   // lane^2
  bmerged<0x141>(a);  // mirror within 8
  // lane g takes the g-th best head -> its list id L (idx field in low 31 bits)
  const unsigned l0 = (unsigned)__double_as_longlong(a[0]);
  const unsigned l1 = (unsigned)__double_as_longlong(a[1]);
  const unsigned l2 = (unsigned)__double_as_longlong(a[2]);
  const unsigned l3 = (unsigned)__double_as_longlong(a[3]);
  const unsigned l4 = (unsigned)__double_as_longlong(a[4]);
  const unsigned l5 = (unsigned)__double_as_longlong(a[5]);
  const unsigned l6 = (unsigned)__double_as_longlong(a[6]);
  const unsigned l7 = (unsigned)__double_as_longlong(a[7]);
  const unsigned lo01 = g1 ? l1 : l0;
  const unsigned lo23 = g1 ? l3 : l2;
  const unsigned lo45 = g1 ? l5 : l4;
  const unsigned lo67 = g1 ? l7 : l6;
  const unsigned loA = g2 ? lo23 : lo01;
  const unsigned loB = g2 ? lo67 : lo45;
  const unsigned sel = (g4 ? loB : loA) & 0x7FFFFFFFu;
  const int L = (int)((0x7FFFFFFFu - sel) >> 3);
  // ---- Phase B ----
  const float trL = trans_colj[(size_t)L * kTAG];
  const float sB = WITHLG ? (lg + trL) : trL;
  const float4* prow = (const float4*)&rows[L][0];
  const float4 r0 = prow[0], r1 = prow[1];
  const unsigned nb = 0x7FFFFFFFu - (unsigned)(L << 3);   // element n -> nb - n
  double q[8];
  q[0] = vk_keyd(sB + r0.x, nb - 0); q[1] = vk_keyd(sB + r0.y, nb - 1);
  q[2] = vk_keyd(sB + r0.z, nb - 2); q[3] = vk_keyd(sB + r0.w, nb - 3);
  q[4] = vk_keyd(sB + r1.x, nb - 4); q[5] = vk_keyd(sB + r1.y, nb - 5);
  q[6] = vk_keyd(sB + r1.z, nb - 6); q[7] = vk_keyd(sB + r1.w, nb - 7);
  bmerged<0xB1>(q);
  bmerged<0x4E>(q);
  bmerged<0x141>(q);
  #pragma unroll
  for (int r = 0; r < 8; ++r) {
    vout[r] = vk_vald(q[r]);
    iout[r] = vk_idxd(q[r]);
  }
}

__global__ __launch_bounds__(256) void k_viterbi(
    const float* __restrict__ logits, const int* __restrict__ mask,
    const float* __restrict__ trans, unsigned short* __restrict__ bps,
    int* __restrict__ lastpos_g, int* __restrict__ ptr0_g)
{
  constexpr int kNT = 31;   // normal tags 0..30
  __shared__ __align__(16) float trans_s[kTAG][kTAG];
  __shared__ __align__(16) float part[2][kNT][12];   // rows padded to 12 floats
  __shared__ __align__(16) float lastp[kNT][12];
  __shared__ int lastpos_s;
  const int b = blockIdx.x, tid = threadIdx.x;
  for (int idx = tid; idx < kTAG * kTAG; idx += 256)
    trans_s[idx / kTAG][idx % kTAG] = trans[idx];
  if (tid < 64) {
    int sm = 0;
    #pragma unroll
    for (int q = 0; q < 8; ++q) sm += mask[b * kS + tid * 8 + q];
    #pragma unroll
    for (int m = 1; m < 64; m <<= 1) sm += __shfl_xor(sm, m, 64);
    if (tid == 0) { lastpos_s = sm - 1; lastpos_g[b] = sm - 1; }
  }
  const int grp = tid >> 3, g = tid & 7;
  const bool active = (grp < kNT);
  const int j = grp;                       // grp==31 inactive (reads col 31, harmless)
  const bool g1 = g & 1, g2 = g & 2, g4 = g & 4;
  __syncthreads();
  float tr[4]; int ii[4]; bool vld[4];
  #pragma unroll
  for (int c = 0; c < 4; ++c) {
    const int i0 = g + 8 * c;
    vld[c] = (i0 < kNT);
    ii[c] = vld[c] ? i0 : 0;
    tr[c] = trans_s[ii[c]][j];
  }
  if (active)
    part[0][j][g] = (g == 0) ? (logits[(size_t)b * kS * kTAG + j] + trans_s[kSTART][j]) : kNEG;
  const int lp = lastpos_s;                // >= 255 (lengths in [S/2, S])
  float lg_next = logits[((size_t)b * kS + 1) * kTAG + j];

  for (int t = 1; t < kS; ++t) {
    __syncthreads();
    if (t <= lp) {                         // block-uniform; mask[t]==1 here
      const float lg = lg_next;
      if (t + 1 <= lp) lg_next = logits[((size_t)b * kS + t + 1) * kTAG + j];
      if (active) {
        float vout[8]; int iout[8];
        merge31<true>(part[(t - 1) & 1], &trans_s[0][j], lg, tr, ii, vld, g1, g2, g4, vout, iout);
        if (g == 0) {
          *(float4*)&part[t & 1][j][0] = make_float4(vout[0], vout[1], vout[2], vout[3]);
          *(float4*)&part[t & 1][j][4] = make_float4(vout[4], vout[5], vout[6], vout[7]);
          if (t == lp) {
            *(float4*)&lastp[j][0] = make_float4(vout[0], vout[1], vout[2], vout[3]);
            *(float4*)&lastp[j][4] = make_float4(vout[4], vout[5], vout[6], vout[7]);
          }
          const unsigned w01 = (unsigned)iout[0] | ((unsigned)iout[1] << 16);
          const unsigned w23 = (unsigned)iout[2] | ((unsigned)iout[3] << 16);
          const unsigned w45 = (unsigned)iout[4] | ((unsigned)iout[5] << 16);
          const unsigned w67 = (unsigned)iout[6] | ((unsigned)iout[7] << 16);
          *(int4*)(bps + ((size_t)t * kB + b) * (kTAG * kNB) + j * kNB) =
              make_int4((int)w01, (int)w23, (int)w45, (int)w67);
        }
      }
    } else if (active && g == 0) {         // dead region: reference stores bp=0
      *(int4*)(bps + ((size_t)t * kB + b) * (kTAG * kNB) + j * kNB) = make_int4(0, 0, 0, 0);
    }
  }
  __syncthreads();
  if (tid < 8) {                           // end merge: column STOP over lastp
    float tre[4];
    #pragma unroll
    for (int c = 0; c < 4; ++c) tre[c] = trans_s[ii[c]][kSTOP];
    float vo[8]; int io[8];
    merge31<false>(lastp, &trans_s[0][kSTOP], 0.f, tre, ii, vld, g1, g2, g4, vo, io);
    if (tid == 0) {
      *(int4*)&ptr0_g[b * kNB + 0] = make_int4(io[0], io[1], io[2], io[3]);
      *(int4*)&ptr0_g[b * kNB + 4] = make_int4(io[4], io[5], io[6], io[7]);
    }
  }
}

// ------- K5: backtrace, per-batch block with LDS-prefetched bp rows ---------
__global__ __launch_bounds__(256) void k_backtrace(
    const unsigned short* __restrict__ bps, const int* __restrict__ ptr0,
    const int* __restrict__ lastpos, const int* __restrict__ mask,
    int* __restrict__ out)
{
  __shared__ uint4 buf[2][4][33];          // 4 rows x 264 u16 per stage
  __shared__ int ptr0_s[kNB];
  __shared__ int mask_s[kS];
  const int b = blockIdx.x, tid = threadIdx.x;
  if (tid < kNB) ptr0_s[tid] = ptr0[b * kNB + tid];
  for (int i = tid; i < kS; i += 256) mask_s[i] = mask[b * kS + i];
  const int lp = lastpos[b];
  const int lr = tid / 33, lc = tid % 33;
  if (tid < 132)
    buf[0][lr][lc] = ((const uint4*)(bps + ((size_t)(kS - 1 - lr) * kB + b) * (kTAG * kNB)))[lc];
  int p = ptr0[b * kNB];
  if (tid == 0) out[b * kS + kS - 1] = p >> 3;
  __syncthreads();
  int cur = 0, tau = kS - 2;
  while (tau >= 0) {
    const int cnt = (tau >= 3) ? 4 : (tau + 1);
    const int ntau = tau - cnt;
    uint4 v; bool have = false;
    if (ntau >= 0 && tid < 132) {
      const int cnt2 = (ntau >= 3) ? 4 : (ntau + 1);
      if (lr < cnt2) {
        v = ((const uint4*)(bps + ((size_t)(ntau + 1 - lr) * kB + b) * (kTAG * kNB)))[lc];
        have = true;
      }
    }
    for (int s2 = 0; s2 < cnt; ++s2) {
      const int t2 = tau - s2;
      int np;
      if (t2 == lp) np = ptr0_s[p & 7];
      else np = ((const unsigned short*)&buf[cur][s2][0])[p];
      if (tid == 0) out[b * kS + t2] = np >> 3;
      p = mask_s[t2] ? np : (np + p);
    }
    __syncthreads();
    if (have) buf[cur ^ 1][lr][lc] = v;
    __syncthreads();
    cur ^= 1; tau = ntau;
  }
}

extern "C" void kernel_launch(void* const* d_in, const int* in_sizes, int n_in,
                              void* d_out, int out_size, void* d_ws, size_t ws_size,
                              hipStream_t stream) {
  if (ws_size < kWsNeed) return;  // fail loudly rather than corrupt memory
  const float* X   = (const float*)d_in[0];
  const int*   msk = (const int*)d_in[1];
  const float* wq  = (const float*)d_in[2];
  const float* wk  = (const float*)d_in[3];
  const float* wv  = (const float*)d_in[4];
  const float* pw  = (const float*)d_in[5];
  const float* pb  = (const float*)d_in[6];
  const float* lng = (const float*)d_in[7];
  const float* lnb = (const float*)d_in[8];
  const float* w1  = (const float*)d_in[9];
  const float* b1  = (const float*)d_in[10];
  const float* w2  = (const float*)d_in[11];
  const float* b2  = (const float*)d_in[12];
  const float* trn = (const float*)d_in[13];
  float* ws = (float*)d_ws;

  k_qkv<<<dim3(128, 9), 256, 0, stream>>>(X, wq, wk, wv, ws);
  k_attn<<<dim3(64, 3, 8), 256, 0, stream>>>(ws + kQOFF, ws + kKOFF, ws + kVOFF, ws + kOAOFF);
  k_head<<<2048, 256, 0, stream>>>(X, ws + kOAOFF, pw, pb, lng, lnb, w1, b1, w2, b2, ws);
  unsigned short* bps = (unsigned short*)((char*)d_ws + kBpsByte);
  int* lastpos_p = (int*)(ws + kKOFF);   // K buffer dead after attention
  int* ptr0_p = lastpos_p + kB;
  k_viterbi<<<kB, 256, 0, stream>>>(ws, msk, trn, bps, lastpos_p, ptr0_p);
  k_backtrace<<<kB, 256, 0, stream>>>(bps, ptr0_p, lastpos_p, msk, (int*)d_out);
}